// Round 2
// baseline (14778.123 us; speedup 1.0000x reference)
//
#include <hip/hip_runtime.h>

#define Bsz  4
#define Lsz  4096
#define Csz  1024
#define NHsz 16
#define CSsz 16
#define HFsz 64
#define HF4sz 256
#define NCsz 256

// ---------------------------------------------------------------------------
// fp32 GEMM: C[M,N] = A[M,K] @ B[K,N].  64x64 tile, BK=16, 4x4 microtile.
// (unchanged)
// ---------------------------------------------------------------------------
__global__ __launch_bounds__(256)
void gemm64(const float* __restrict__ A, const float* __restrict__ Bm,
            float* __restrict__ Cm, int M, int N, int K)
{
  __shared__ __attribute__((aligned(16))) float As[16][68];
  __shared__ __attribute__((aligned(16))) float Bs[16][64];
  const int t  = threadIdx.x;
  const int tx = t & 15, ty = t >> 4;
  const int row0 = blockIdx.y * 64, col0 = blockIdx.x * 64;
  const int ar = t >> 2, ak = (t & 3) * 4;
  const int bk = t >> 4, bc = (t & 15) * 4;
  float acc[4][4] = {};

  for (int k0 = 0; k0 < K; k0 += 16) {
    float4 a4 = *(const float4*)&A[(size_t)(row0 + ar) * K + k0 + ak];
    float4 b4 = *(const float4*)&Bm[(size_t)(k0 + bk) * N + col0 + bc];
    As[ak + 0][ar] = a4.x; As[ak + 1][ar] = a4.y;
    As[ak + 2][ar] = a4.z; As[ak + 3][ar] = a4.w;
    *(float4*)&Bs[bk][bc] = b4;
    __syncthreads();
#pragma unroll
    for (int kk = 0; kk < 16; ++kk) {
      float4 av = *(const float4*)&As[kk][ty * 4];
      float4 bv = *(const float4*)&Bs[kk][tx * 4];
      acc[0][0] += av.x * bv.x; acc[0][1] += av.x * bv.y;
      acc[0][2] += av.x * bv.z; acc[0][3] += av.x * bv.w;
      acc[1][0] += av.y * bv.x; acc[1][1] += av.y * bv.y;
      acc[1][2] += av.y * bv.z; acc[1][3] += av.y * bv.w;
      acc[2][0] += av.z * bv.x; acc[2][1] += av.z * bv.y;
      acc[2][2] += av.z * bv.z; acc[2][3] += av.z * bv.w;
      acc[3][0] += av.w * bv.x; acc[3][1] += av.w * bv.y;
      acc[3][2] += av.w * bv.z; acc[3][3] += av.w * bv.w;
    }
    __syncthreads();
  }
#pragma unroll
  for (int r = 0; r < 4; ++r) {
    float4 v = make_float4(acc[r][0], acc[r][1], acc[r][2], acc[r][3]);
    *(float4*)&Cm[(size_t)(row0 + ty * 4 + r) * N + col0 + tx * 4] = v;
  }
}

// ---------------------------------------------------------------------------
// ilr -> coeff table (unchanged)
// ---------------------------------------------------------------------------
__global__ __launch_bounds__(256)
void ilr_coeff(const float* __restrict__ H, const float* __restrict__ Wil,
               const float* __restrict__ bil, float* __restrict__ coeff)
{
  __shared__ float sRow[4][1024];
  __shared__ float sP[4][16][17];
  const int t = threadIdx.x;
  const size_t r0 = (size_t)blockIdx.x * 4;
  for (int rr = 0; rr < 4; ++rr)
    for (int c = t; c < 1024; c += 256)
      sRow[rr][c] = H[(r0 + rr) * 1024 + c];
  __syncthreads();
  const int hh = t & 15, sl = t >> 4;
  for (int rr = 0; rr < 4; ++rr) {
    float acc = 0.f;
    for (int kk = 0; kk < 64; ++kk)
      acc += sRow[rr][sl * 64 + kk] * Wil[(sl * 64 + kk) * 16 + hh];
    sP[rr][sl][hh] = acc;
  }
  __syncthreads();
  if (t < 64) {
    const int rr = t >> 4, h2 = t & 15;
    float s = 0.f;
    for (int sl2 = 0; sl2 < 16; ++sl2) s += sP[rr][sl2][h2];
    s += bil[h2];
    const float sig = 1.f / (1.f + expf(-s));
    const int r  = (int)(r0 + rr);
    const int b  = r >> 12, l = r & 4095, nc = l >> 4, cs = l & 15;
    coeff[((b * 16 + h2) * NCsz + nc) * CSsz + cs] = sig / ((float)(cs + 1) * 64.0f);
  }
}

// ---------------------------------------------------------------------------
// TTT scan v3.  Same phase structure as v2.
//
// Round-1 post-mortem: v2 regressed because the scheduler locked a 128-VGPR
// (4 waves/EU) occupancy target and spilled ~60 regs/thread in the B-group
// (w2r[64]+w2c[64]=128 persistent alone) -> +125 MB scratch writes, stalls.
// Grid is 64 blocks on 256 CUs -> at most 1 block/CU EVER, so occupancy
// above 2 waves/EU (one 8-wave block) is unreachable.  Force the allocator
// to use the full 256-VGPR budget with amdgpu_waves_per_eu(1,2).
// Also: coA[16] register array dropped (read sCoBuf directly in P5).
// ---------------------------------------------------------------------------
__global__ __launch_bounds__(512) __attribute__((amdgpu_waves_per_eu(1, 2)))
void ttt_scan(const float* __restrict__ XA, const float* __restrict__ XBuf,
              const float* __restrict__ XCbuf, const float* __restrict__ coeff,
              const float* __restrict__ W1g, const float* __restrict__ W2g,
              float* __restrict__ Out)
{
  __shared__ __attribute__((aligned(16))) float sXB[2][16 * 68];
  __shared__ __attribute__((aligned(16))) float sXC[2][16 * 68];
  __shared__ __attribute__((aligned(16))) float sg2[16 * 68];
  __shared__ __attribute__((aligned(16))) float sZ1[16 * 260];
  __shared__ __attribute__((aligned(16))) float sZ1b[16 * 260];
  __shared__ __attribute__((aligned(16))) float sTmp[4096]; // [4][16][64] partials | [16][256] g1
  __shared__ float sA1[16 * 17];
  __shared__ float sA2[16 * 17];
  __shared__ float sCoBuf[2 * 16];

  const int t   = threadIdx.x;
  const int bh  = blockIdx.x;             // 0..63
  const int b   = bh >> 4, h = bh & 15;
  const bool isA = (t < 256);
  const int n   = t & 255;                // A: W1 column / B: W2 row
  const int m   = t & 63, q = (t >> 6) & 3;

  float w1[64];    // A only
  float w2r[64];   // B only
  float w2c[64];   // B only
  float zb[16];    // A: z1bp (P2) -> Z1b (P5)
  float g1v[16];   // A: g1 column (P5 -> P6)
  float xa0, xa1;  // XA prefetch (all threads)

  const float* W1h = W1g + h * HFsz * HF4sz;
  const float* W2h = W2g + h * HF4sz * HFsz;
  if (isA) {
#pragma unroll
    for (int k = 0; k < 64; ++k) w1[k] = W1h[k * 256 + n];
  } else {
#pragma unroll
    for (int mm = 0; mm < 64; ++mm) w2r[mm] = W2h[n * 64 + mm];
#pragma unroll
    for (int kk = 0; kk < 64; ++kk) w2c[kk] = W2h[(q * 64 + kk) * 64 + m];
  }

  // ---- pre-loop: stage chunk 0 ------------------------------------------
  {
    const int cb0 = (b * Lsz) * Csz + h * HFsz;
    if (!isA) {
      const int row = n >> 4, col4 = (n & 15) * 4;
      *(float4*)&sXB[0][row * 68 + col4] = *(const float4*)&XBuf [cb0 + row * 1024 + col4];
      *(float4*)&sXC[0][row * 68 + col4] = *(const float4*)&XCbuf[cb0 + row * 1024 + col4];
    }
    if (t < 16) sCoBuf[t] = coeff[(bh * NCsz + 0) * CSsz + t];
    const int ibr = t >> 6, mm = t & 63;
    xa0 = XA[cb0 + ibr * 1024 + mm];
    xa1 = XA[cb0 + (ibr + 8) * 1024 + mm];
  }
  __syncthreads();

#pragma unroll 1
  for (int nc = 0; nc < NCsz; ++nc) {
    const int cur = nc & 1, nxt = cur ^ 1;
    const int cb  = (b * Lsz + nc * CSsz) * Csz + h * HFsz;
    const int nc1 = (nc + 1) & (NCsz - 1);
    const int cb1 = (b * Lsz + nc1 * CSsz) * Csz + h * HFsz;
    const float* sXBc = &sXB[cur][0];
    const float* sXCc = &sXC[cur][0];

    // ---- chunk top: coeff + next-chunk prefetch (regs only) -------------
    const float cl = sCoBuf[cur * 16 + 15];
    float conext = 0.f;
    float4 vnb, vnc;
    if (isA) {
      if (t < 16) conext = coeff[(bh * NCsz + nc1) * CSsz + t];
    } else {
      const int row = n >> 4, col4 = (n & 15) * 4;
      vnb = *(const float4*)&XBuf [cb1 + row * 1024 + col4];
      vnc = *(const float4*)&XCbuf[cb1 + row * 1024 + col4];
    }

    // ---- P1: A: Z1 = XB@W1 -> sZ1   | B: Attn1 = tril(XC@XB^T) ----------
    if (isA) {
      float acc[16];
#pragma unroll
      for (int i = 0; i < 16; ++i) acc[i] = 0.f;
#pragma unroll
      for (int k = 0; k < 64; k += 4) {
        const float wa = w1[k], wb = w1[k + 1], wc = w1[k + 2], wd = w1[k + 3];
#pragma unroll
        for (int i = 0; i < 16; ++i) {
          const float4 x = *(const float4*)&sXBc[i * 68 + k];
          acc[i] = fmaf(x.w, wd, fmaf(x.z, wc, fmaf(x.y, wb, fmaf(x.x, wa, acc[i]))));
        }
      }
#pragma unroll
      for (int i = 0; i < 16; ++i) sZ1[i * 260 + n] = acc[i];
    } else {
      const int ia = n >> 4, ja = n & 15;
      float a0 = 0.f, a1 = 0.f;
      if (ja <= ia) {
#pragma unroll
        for (int k = 0; k < 64; k += 8) {
          const float4 c0 = *(const float4*)&sXCc[ia * 68 + k];
          const float4 b0 = *(const float4*)&sXBc[ja * 68 + k];
          const float4 c1 = *(const float4*)&sXCc[ia * 68 + k + 4];
          const float4 b1 = *(const float4*)&sXBc[ja * 68 + k + 4];
          a0 = fmaf(c0.w, b0.w, fmaf(c0.z, b0.z, fmaf(c0.y, b0.y, fmaf(c0.x, b0.x, a0))));
          a1 = fmaf(c1.w, b1.w, fmaf(c1.z, b1.z, fmaf(c1.y, b1.y, fmaf(c1.x, b1.x, a1))));
        }
      }
      sA1[ia * 17 + ja] = a0 + a1;
    }
    __syncthreads();

    // ---- P2: A: z1bp = XC@W1 -> zb regs | B: Z2 partials -> sTmp --------
    if (isA) {
#pragma unroll
      for (int i = 0; i < 16; ++i) zb[i] = 0.f;
#pragma unroll
      for (int k = 0; k < 64; k += 4) {
        const float wa = w1[k], wb = w1[k + 1], wc = w1[k + 2], wd = w1[k + 3];
#pragma unroll
        for (int i = 0; i < 16; ++i) {
          const float4 x = *(const float4*)&sXCc[i * 68 + k];
          zb[i] = fmaf(x.w, wd, fmaf(x.z, wc, fmaf(x.y, wb, fmaf(x.x, wa, zb[i]))));
        }
      }
    } else {
      const int qo = q << 6;
      float acc[16];
#pragma unroll
      for (int i = 0; i < 16; ++i) acc[i] = 0.f;
#pragma unroll
      for (int kk = 0; kk < 64; kk += 4) {
        const float wa = w2c[kk], wb = w2c[kk + 1], wc = w2c[kk + 2], wd = w2c[kk + 3];
#pragma unroll
        for (int i = 0; i < 16; ++i) {
          const float4 z = *(const float4*)&sZ1[i * 260 + qo + kk];
          acc[i] = fmaf(z.w, wd, fmaf(z.z, wc, fmaf(z.y, wb, fmaf(z.x, wa, acc[i]))));
        }
      }
#pragma unroll
      for (int i = 0; i < 16; ++i) sTmp[(q << 10) + (i << 6) + m] = acc[i];
    }
    __syncthreads();

    // ---- P3: all: g2 = reduce(Z2 partials) - XA -> sg2 ; stage coeff ----
    {
      const int ibr = t >> 6, mm = t & 63;
      const int i1 = ibr + 8;
      float v0 = sTmp[ibr * 64 + mm] + sTmp[1024 + ibr * 64 + mm]
               + sTmp[2048 + ibr * 64 + mm] + sTmp[3072 + ibr * 64 + mm] - xa0;
      float v1 = sTmp[i1 * 64 + mm] + sTmp[1024 + i1 * 64 + mm]
               + sTmp[2048 + i1 * 64 + mm] + sTmp[3072 + i1 * 64 + mm] - xa1;
      sg2[ibr * 68 + mm] = v0;
      sg2[i1 * 68 + mm]  = v1;
      // prefetch next chunk's XA (consumed next P3)
      xa0 = XA[cb1 + ibr * 1024 + mm];
      xa1 = XA[cb1 + i1 * 1024 + mm];
      if (t < 16) sCoBuf[nxt * 16 + t] = conext;
    }
    __syncthreads();

    // ---- P4: B: g1 = g2@W2^T -> sTmp[16][256]  +  W2 row update ---------
    //      (same sg2 float4 stream feeds both; g1 uses pre-update w2r)
    if (!isA) {
      float s[16];
#pragma unroll
      for (int i = 0; i < 16; ++i) s[i] = cl * sZ1[i * 260 + n];
      float acc[16];
#pragma unroll
      for (int i = 0; i < 16; ++i) acc[i] = 0.f;
#pragma unroll
      for (int mm = 0; mm < 64; mm += 4) {
        const float wa = w2r[mm], wb = w2r[mm + 1], wc = w2r[mm + 2], wd = w2r[mm + 3];
        float d0 = 0.f, d1 = 0.f, d2 = 0.f, d3 = 0.f;
#pragma unroll
        for (int i = 0; i < 16; ++i) {
          const float4 g = *(const float4*)&sg2[i * 68 + mm];
          acc[i] = fmaf(g.w, wd, fmaf(g.z, wc, fmaf(g.y, wb, fmaf(g.x, wa, acc[i]))));
          d0 = fmaf(s[i], g.x, d0); d1 = fmaf(s[i], g.y, d1);
          d2 = fmaf(s[i], g.z, d2); d3 = fmaf(s[i], g.w, d3);
        }
        w2r[mm + 0] -= d0; w2r[mm + 1] -= d1; w2r[mm + 2] -= d2; w2r[mm + 3] -= d3;
      }
#pragma unroll
      for (int i = 0; i < 16; ++i) sTmp[i * 256 + n] = acc[i];
    }
    __syncthreads();

    // ---- P5: A: Z1b finalize -> sZ1b | B: stage next XB/XC tiles --------
    if (isA) {
#pragma unroll
      for (int j = 0; j < 16; ++j) g1v[j] = sTmp[j * 256 + n];
#pragma unroll
      for (int i = 0; i < 16; ++i) {
        float at = 0.f;
#pragma unroll
        for (int j = 0; j <= i; ++j) at = fmaf(sA1[i * 17 + j], g1v[j], at);
        zb[i] = fmaf(-sCoBuf[cur * 16 + i], at, zb[i]);
        sZ1b[i * 260 + n] = zb[i];
      }
    } else {
      const int row = n >> 4, col4 = (n & 15) * 4;
      *(float4*)&sXB[nxt][row * 68 + col4] = vnb;
      *(float4*)&sXC[nxt][row * 68 + col4] = vnc;
    }
    __syncthreads();

    // ---- P6: A: Attn2 + W1 update | B: Z2b partials + W2 col update -----
    if (isA) {
      const int ia = n >> 4, ja = n & 15;
      float a0 = 0.f, a1 = 0.f, a2 = 0.f, a3 = 0.f;
      if (ja <= ia) {
#pragma unroll
        for (int kk = 0; kk < 256; kk += 16) {
          const float4 p0 = *(const float4*)&sZ1b[ia * 260 + kk];
          const float4 z0 = *(const float4*)&sZ1 [ja * 260 + kk];
          const float4 p1 = *(const float4*)&sZ1b[ia * 260 + kk + 4];
          const float4 z1 = *(const float4*)&sZ1 [ja * 260 + kk + 4];
          const float4 p2 = *(const float4*)&sZ1b[ia * 260 + kk + 8];
          const float4 z2 = *(const float4*)&sZ1 [ja * 260 + kk + 8];
          const float4 p3 = *(const float4*)&sZ1b[ia * 260 + kk + 12];
          const float4 z3 = *(const float4*)&sZ1 [ja * 260 + kk + 12];
          a0 = fmaf(p0.w, z0.w, fmaf(p0.z, z0.z, fmaf(p0.y, z0.y, fmaf(p0.x, z0.x, a0))));
          a1 = fmaf(p1.w, z1.w, fmaf(p1.z, z1.z, fmaf(p1.y, z1.y, fmaf(p1.x, z1.x, a1))));
          a2 = fmaf(p2.w, z2.w, fmaf(p2.z, z2.z, fmaf(p2.y, z2.y, fmaf(p2.x, z2.x, a2))));
          a3 = fmaf(p3.w, z3.w, fmaf(p3.z, z3.z, fmaf(p3.y, z3.y, fmaf(p3.x, z3.x, a3))));
        }
      }
      sA2[ia * 17 + ja] = (a0 + a1) + (a2 + a3);
      // W1 update: w1[k] -= cl * sum_i g1[i][n] * XB[i][k]
#pragma unroll
      for (int k = 0; k < 64; k += 4) {
        float d0 = 0.f, d1 = 0.f, d2 = 0.f, d3 = 0.f;
#pragma unroll
        for (int i = 0; i < 16; ++i) {
          const float4 x = *(const float4*)&sXBc[i * 68 + k];
          d0 = fmaf(g1v[i], x.x, d0); d1 = fmaf(g1v[i], x.y, d1);
          d2 = fmaf(g1v[i], x.z, d2); d3 = fmaf(g1v[i], x.w, d3);
        }
        w1[k + 0] -= cl * d0; w1[k + 1] -= cl * d1;
        w1[k + 2] -= cl * d2; w1[k + 3] -= cl * d3;
      }
    } else {
      const int qo = q << 6;
      // Z2b partials (pre-update w2c)
      float acc[16];
#pragma unroll
      for (int i = 0; i < 16; ++i) acc[i] = 0.f;
#pragma unroll
      for (int kk = 0; kk < 64; kk += 4) {
        const float wa = w2c[kk], wb = w2c[kk + 1], wc = w2c[kk + 2], wd = w2c[kk + 3];
#pragma unroll
        for (int i = 0; i < 16; ++i) {
          const float4 z = *(const float4*)&sZ1b[i * 260 + qo + kk];
          acc[i] = fmaf(z.w, wd, fmaf(z.z, wc, fmaf(z.y, wb, fmaf(z.x, wa, acc[i]))));
        }
      }
#pragma unroll
      for (int i = 0; i < 16; ++i) sTmp[(q << 10) + (i << 6) + m] = acc[i];
      // W2 col update: w2c[kk] -= cl * sum_i Z1[i][qo+kk] * g2[i][m]
      float s2[16];
#pragma unroll
      for (int i = 0; i < 16; ++i) s2[i] = cl * sg2[i * 68 + m];
#pragma unroll
      for (int kk = 0; kk < 64; kk += 4) {
        float d0 = 0.f, d1 = 0.f, d2 = 0.f, d3 = 0.f;
#pragma unroll
        for (int i = 0; i < 16; ++i) {
          const float4 z = *(const float4*)&sZ1[i * 260 + qo + kk];
          d0 = fmaf(s2[i], z.x, d0); d1 = fmaf(s2[i], z.y, d1);
          d2 = fmaf(s2[i], z.z, d2); d3 = fmaf(s2[i], z.w, d3);
        }
        w2c[kk + 0] -= d0; w2c[kk + 1] -= d1; w2c[kk + 2] -= d2; w2c[kk + 3] -= d3;
      }
    }
    __syncthreads();

    // ---- P7: A: Z2b combine + store (B proceeds; safe: next writes to
    //      sTmp/sA2/sg2/sCoBuf[cur] are >=2 barriers away, P1 writes only
    //      sZ1/sA1 which P7 does not read) -------------------------------
    if (isA) {
      const int q4 = n >> 6, mm = n & 63;
#pragma unroll
      for (int r = 0; r < 4; ++r) {
        const int i = q4 + 4 * r;
        float v = sTmp[i * 64 + mm] + sTmp[1024 + i * 64 + mm]
                + sTmp[2048 + i * 64 + mm] + sTmp[3072 + i * 64 + mm];
        float at = 0.f;
#pragma unroll
        for (int j = 0; j < 16; ++j) at = fmaf(sA2[i * 17 + j], sg2[j * 68 + mm], at);
        Out[cb + i * 1024 + mm] = v - sCoBuf[cur * 16 + i] * at;
      }
    }
  }
}

// ---------------------------------------------------------------------------
// Workspace (fp32 floats): bXC [0,16.7M) | bXB [16.7M,33.5M) | bZ2b
// [33.5M,50.3M) | bCo [50.3M,+262k).  193 MiB total.  XA (V proj) lives in
// d_out until the final GEMM overwrites it (stream-ordered, safe).
// ---------------------------------------------------------------------------
extern "C" void kernel_launch(void* const* d_in, const int* in_sizes, int n_in,
                              void* d_out, int out_size, void* d_ws, size_t ws_size,
                              hipStream_t stream)
{
  const float* H    = (const float*)d_in[0];
  const float* Wq   = (const float*)d_in[1];
  const float* Wk   = (const float*)d_in[2];
  const float* Wv   = (const float*)d_in[3];
  const float* Wo   = (const float*)d_in[4];
  const float* Wil  = (const float*)d_in[5];
  const float* bil  = (const float*)d_in[6];
  const float* W1   = (const float*)d_in[7];
  const float* W2   = (const float*)d_in[8];
  float* out        = (float*)d_out;

  float* ws    = (float*)d_ws;
  float* bXC   = ws;
  float* bXB   = ws + 16777216;
  float* bZ2b  = ws + 33554432;
  float* bCo   = ws + 50331648;
  float* bXA   = out;

  const int M = Bsz * Lsz, N = Csz, K = Csz;
  dim3 gg(N / 64, M / 64);
  dim3 bb(256);

  gemm64<<<gg, bb, 0, stream>>>(H, Wq, bXC, M, N, K);
  gemm64<<<gg, bb, 0, stream>>>(H, Wk, bXB, M, N, K);
  gemm64<<<gg, bb, 0, stream>>>(H, Wv, bXA, M, N, K);
  ilr_coeff<<<M / 4, 256, 0, stream>>>(H, Wil, bil, bCo);
  ttt_scan<<<Bsz * NHsz, 512, 0, stream>>>(bXA, bXB, bXC, bCo, W1, W2, bZ2b);
  gemm64<<<gg, bb, 0, stream>>>(bZ2b, Wo, out, M, N, K);
}

// Round 3
// 11574.787 us; speedup vs baseline: 1.2768x; 1.2768x over previous
//
#include <hip/hip_runtime.h>

#define Bsz  4
#define Lsz  4096
#define Csz  1024
#define NHsz 16
#define CSsz 16
#define HFsz 64
#define HF4sz 256
#define NCsz 256

// ---------------------------------------------------------------------------
// fp32 GEMM: C[M,N] = A[M,K] @ B[K,N].  64x64 tile, BK=16, 4x4 microtile.
// (unchanged)
// ---------------------------------------------------------------------------
__global__ __launch_bounds__(256)
void gemm64(const float* __restrict__ A, const float* __restrict__ Bm,
            float* __restrict__ Cm, int M, int N, int K)
{
  __shared__ __attribute__((aligned(16))) float As[16][68];
  __shared__ __attribute__((aligned(16))) float Bs[16][64];
  const int t  = threadIdx.x;
  const int tx = t & 15, ty = t >> 4;
  const int row0 = blockIdx.y * 64, col0 = blockIdx.x * 64;
  const int ar = t >> 2, ak = (t & 3) * 4;
  const int bk = t >> 4, bc = (t & 15) * 4;
  float acc[4][4] = {};

  for (int k0 = 0; k0 < K; k0 += 16) {
    float4 a4 = *(const float4*)&A[(size_t)(row0 + ar) * K + k0 + ak];
    float4 b4 = *(const float4*)&Bm[(size_t)(k0 + bk) * N + col0 + bc];
    As[ak + 0][ar] = a4.x; As[ak + 1][ar] = a4.y;
    As[ak + 2][ar] = a4.z; As[ak + 3][ar] = a4.w;
    *(float4*)&Bs[bk][bc] = b4;
    __syncthreads();
#pragma unroll
    for (int kk = 0; kk < 16; ++kk) {
      float4 av = *(const float4*)&As[kk][ty * 4];
      float4 bv = *(const float4*)&Bs[kk][tx * 4];
      acc[0][0] += av.x * bv.x; acc[0][1] += av.x * bv.y;
      acc[0][2] += av.x * bv.z; acc[0][3] += av.x * bv.w;
      acc[1][0] += av.y * bv.x; acc[1][1] += av.y * bv.y;
      acc[1][2] += av.y * bv.z; acc[1][3] += av.y * bv.w;
      acc[2][0] += av.z * bv.x; acc[2][1] += av.z * bv.y;
      acc[2][2] += av.z * bv.z; acc[2][3] += av.z * bv.w;
      acc[3][0] += av.w * bv.x; acc[3][1] += av.w * bv.y;
      acc[3][2] += av.w * bv.z; acc[3][3] += av.w * bv.w;
    }
    __syncthreads();
  }
#pragma unroll
  for (int r = 0; r < 4; ++r) {
    float4 v = make_float4(acc[r][0], acc[r][1], acc[r][2], acc[r][3]);
    *(float4*)&Cm[(size_t)(row0 + ty * 4 + r) * N + col0 + tx * 4] = v;
  }
}

// ---------------------------------------------------------------------------
// ilr -> coeff table (unchanged)
// ---------------------------------------------------------------------------
__global__ __launch_bounds__(256)
void ilr_coeff(const float* __restrict__ H, const float* __restrict__ Wil,
               const float* __restrict__ bil, float* __restrict__ coeff)
{
  __shared__ float sRow[4][1024];
  __shared__ float sP[4][16][17];
  const int t = threadIdx.x;
  const size_t r0 = (size_t)blockIdx.x * 4;
  for (int rr = 0; rr < 4; ++rr)
    for (int c = t; c < 1024; c += 256)
      sRow[rr][c] = H[(r0 + rr) * 1024 + c];
  __syncthreads();
  const int hh = t & 15, sl = t >> 4;
  for (int rr = 0; rr < 4; ++rr) {
    float acc = 0.f;
    for (int kk = 0; kk < 64; ++kk)
      acc += sRow[rr][sl * 64 + kk] * Wil[(sl * 64 + kk) * 16 + hh];
    sP[rr][sl][hh] = acc;
  }
  __syncthreads();
  if (t < 64) {
    const int rr = t >> 4, h2 = t & 15;
    float s = 0.f;
    for (int sl2 = 0; sl2 < 16; ++sl2) s += sP[rr][sl2][h2];
    s += bil[h2];
    const float sig = 1.f / (1.f + expf(-s));
    const int r  = (int)(r0 + rr);
    const int b  = r >> 12, l = r & 4095, nc = l >> 4, cs = l & 15;
    coeff[((b * 16 + h2) * NCsz + nc) * CSsz + cs] = sig / ((float)(cs + 1) * 64.0f);
  }
}

// ---------------------------------------------------------------------------
// TTT scan v4.  Same phase structure as v2/v3.
//
// Round-2 post-mortem: VGPR stuck at 128 because the allocator targets the
// LDS-derived occupancy: 73728B LDS -> 2 WGs/CU fit -> 4 waves/EU -> 128-reg
// cap -> ~70MB spill traffic.  But the grid is 64 blocks on 256 CUs, so
// >1 WG/CU never happens.  Fixes:
//  (a) pad LDS past 80KB (sTmp 4096->6272) so only 1 WG/CU fits -> the
//      heuristic's own target becomes 2 waves/EU -> 256-VGPR budget.
//  (b) overlay A/B persistent state in ONE wreg[128] array (allocation is
//      per-thread over the UNION of both specialization branches; separate
//      w1[64]+w2r[64]+w2c[64] arrays = 192 persistent regs even though no
//      thread uses both).  A: w1=[0:64], zb=[64:80], g1v=[80:96].
//      B: w2r=[0:64], w2c=[64:128].  All indices compile-time constant.
// ---------------------------------------------------------------------------
__global__ __launch_bounds__(512) __attribute__((amdgpu_waves_per_eu(1, 2)))
void ttt_scan(const float* __restrict__ XA, const float* __restrict__ XBuf,
              const float* __restrict__ XCbuf, const float* __restrict__ coeff,
              const float* __restrict__ W1g, const float* __restrict__ W2g,
              float* __restrict__ Out)
{
  __shared__ __attribute__((aligned(16))) float sXB[2][16 * 68];
  __shared__ __attribute__((aligned(16))) float sXC[2][16 * 68];
  __shared__ __attribute__((aligned(16))) float sg2[16 * 68];
  __shared__ __attribute__((aligned(16))) float sZ1[16 * 260];
  __shared__ __attribute__((aligned(16))) float sZ1b[16 * 260];
  // 6272 floats: first 4096 used ([4][16][64] partials | [16][256] g1);
  // tail is padding that pushes total LDS to 82432B -> only 1 WG/CU fits,
  // so the compiler's occupancy target drops to 2 waves/EU (256-VGPR budget).
  __shared__ __attribute__((aligned(16))) float sTmp[6272];
  __shared__ float sA1[16 * 17];
  __shared__ float sA2[16 * 17];
  __shared__ float sCoBuf[2 * 16];

  const int t   = threadIdx.x;
  const int bh  = blockIdx.x;             // 0..63
  const int b   = bh >> 4, h = bh & 15;
  const bool isA = (t < 256);
  const int n   = t & 255;                // A: W1 column / B: W2 row
  const int m   = t & 63, q = (t >> 6) & 3;

  // Overlaid persistent state (see header comment).
  float wreg[128];
#define W1R(k)  wreg[(k)]
#define ZBR(i)  wreg[64 + (i)]
#define G1R(i)  wreg[80 + (i)]
#define W2RR(k) wreg[(k)]
#define W2CR(k) wreg[64 + (k)]

  float xa0, xa1;  // XA prefetch (all threads)

  const float* W1h = W1g + h * HFsz * HF4sz;
  const float* W2h = W2g + h * HF4sz * HFsz;
  if (isA) {
#pragma unroll
    for (int k = 0; k < 64; ++k) W1R(k) = W1h[k * 256 + n];
  } else {
#pragma unroll
    for (int mm = 0; mm < 64; ++mm) W2RR(mm) = W2h[n * 64 + mm];
#pragma unroll
    for (int kk = 0; kk < 64; ++kk) W2CR(kk) = W2h[(q * 64 + kk) * 64 + m];
  }

  // ---- pre-loop: stage chunk 0 ------------------------------------------
  {
    const int cb0 = (b * Lsz) * Csz + h * HFsz;
    if (!isA) {
      const int row = n >> 4, col4 = (n & 15) * 4;
      *(float4*)&sXB[0][row * 68 + col4] = *(const float4*)&XBuf [cb0 + row * 1024 + col4];
      *(float4*)&sXC[0][row * 68 + col4] = *(const float4*)&XCbuf[cb0 + row * 1024 + col4];
    }
    if (t < 16) sCoBuf[t] = coeff[(bh * NCsz + 0) * CSsz + t];
    const int ibr = t >> 6, mm = t & 63;
    xa0 = XA[cb0 + ibr * 1024 + mm];
    xa1 = XA[cb0 + (ibr + 8) * 1024 + mm];
  }
  __syncthreads();

#pragma unroll 1
  for (int nc = 0; nc < NCsz; ++nc) {
    const int cur = nc & 1, nxt = cur ^ 1;
    const int cb  = (b * Lsz + nc * CSsz) * Csz + h * HFsz;
    const int nc1 = (nc + 1) & (NCsz - 1);
    const int cb1 = (b * Lsz + nc1 * CSsz) * Csz + h * HFsz;
    const float* sXBc = &sXB[cur][0];
    const float* sXCc = &sXC[cur][0];

    // ---- chunk top: coeff + next-chunk prefetch (regs only) -------------
    const float cl = sCoBuf[cur * 16 + 15];
    float conext = 0.f;
    float4 vnb, vnc;
    if (isA) {
      if (t < 16) conext = coeff[(bh * NCsz + nc1) * CSsz + t];
    } else {
      const int row = n >> 4, col4 = (n & 15) * 4;
      vnb = *(const float4*)&XBuf [cb1 + row * 1024 + col4];
      vnc = *(const float4*)&XCbuf[cb1 + row * 1024 + col4];
    }

    // ---- P1: A: Z1 = XB@W1 -> sZ1   | B: Attn1 = tril(XC@XB^T) ----------
    if (isA) {
      float acc[16];
#pragma unroll
      for (int i = 0; i < 16; ++i) acc[i] = 0.f;
#pragma unroll
      for (int k = 0; k < 64; k += 4) {
        const float wa = W1R(k), wb = W1R(k + 1), wc = W1R(k + 2), wd = W1R(k + 3);
#pragma unroll
        for (int i = 0; i < 16; ++i) {
          const float4 x = *(const float4*)&sXBc[i * 68 + k];
          acc[i] = fmaf(x.w, wd, fmaf(x.z, wc, fmaf(x.y, wb, fmaf(x.x, wa, acc[i]))));
        }
      }
#pragma unroll
      for (int i = 0; i < 16; ++i) sZ1[i * 260 + n] = acc[i];
    } else {
      const int ia = n >> 4, ja = n & 15;
      float a0 = 0.f, a1 = 0.f;
      if (ja <= ia) {
#pragma unroll
        for (int k = 0; k < 64; k += 8) {
          const float4 c0 = *(const float4*)&sXCc[ia * 68 + k];
          const float4 b0 = *(const float4*)&sXBc[ja * 68 + k];
          const float4 c1 = *(const float4*)&sXCc[ia * 68 + k + 4];
          const float4 b1 = *(const float4*)&sXBc[ja * 68 + k + 4];
          a0 = fmaf(c0.w, b0.w, fmaf(c0.z, b0.z, fmaf(c0.y, b0.y, fmaf(c0.x, b0.x, a0))));
          a1 = fmaf(c1.w, b1.w, fmaf(c1.z, b1.z, fmaf(c1.y, b1.y, fmaf(c1.x, b1.x, a1))));
        }
      }
      sA1[ia * 17 + ja] = a0 + a1;
    }
    __syncthreads();

    // ---- P2: A: z1bp = XC@W1 -> zb regs | B: Z2 partials -> sTmp --------
    if (isA) {
#pragma unroll
      for (int i = 0; i < 16; ++i) ZBR(i) = 0.f;
#pragma unroll
      for (int k = 0; k < 64; k += 4) {
        const float wa = W1R(k), wb = W1R(k + 1), wc = W1R(k + 2), wd = W1R(k + 3);
#pragma unroll
        for (int i = 0; i < 16; ++i) {
          const float4 x = *(const float4*)&sXCc[i * 68 + k];
          ZBR(i) = fmaf(x.w, wd, fmaf(x.z, wc, fmaf(x.y, wb, fmaf(x.x, wa, ZBR(i)))));
        }
      }
    } else {
      const int qo = q << 6;
      float acc[16];
#pragma unroll
      for (int i = 0; i < 16; ++i) acc[i] = 0.f;
#pragma unroll
      for (int kk = 0; kk < 64; kk += 4) {
        const float wa = W2CR(kk), wb = W2CR(kk + 1), wc = W2CR(kk + 2), wd = W2CR(kk + 3);
#pragma unroll
        for (int i = 0; i < 16; ++i) {
          const float4 z = *(const float4*)&sZ1[i * 260 + qo + kk];
          acc[i] = fmaf(z.w, wd, fmaf(z.z, wc, fmaf(z.y, wb, fmaf(z.x, wa, acc[i]))));
        }
      }
#pragma unroll
      for (int i = 0; i < 16; ++i) sTmp[(q << 10) + (i << 6) + m] = acc[i];
    }
    __syncthreads();

    // ---- P3: all: g2 = reduce(Z2 partials) - XA -> sg2 ; stage coeff ----
    {
      const int ibr = t >> 6, mm = t & 63;
      const int i1 = ibr + 8;
      float v0 = sTmp[ibr * 64 + mm] + sTmp[1024 + ibr * 64 + mm]
               + sTmp[2048 + ibr * 64 + mm] + sTmp[3072 + ibr * 64 + mm] - xa0;
      float v1 = sTmp[i1 * 64 + mm] + sTmp[1024 + i1 * 64 + mm]
               + sTmp[2048 + i1 * 64 + mm] + sTmp[3072 + i1 * 64 + mm] - xa1;
      sg2[ibr * 68 + mm] = v0;
      sg2[i1 * 68 + mm]  = v1;
      // prefetch next chunk's XA (consumed next P3)
      xa0 = XA[cb1 + ibr * 1024 + mm];
      xa1 = XA[cb1 + i1 * 1024 + mm];
      if (t < 16) sCoBuf[nxt * 16 + t] = conext;
    }
    __syncthreads();

    // ---- P4: B: g1 = g2@W2^T -> sTmp[16][256]  +  W2 row update ---------
    //      (same sg2 float4 stream feeds both; g1 uses pre-update w2r)
    if (!isA) {
      float s[16];
#pragma unroll
      for (int i = 0; i < 16; ++i) s[i] = cl * sZ1[i * 260 + n];
      float acc[16];
#pragma unroll
      for (int i = 0; i < 16; ++i) acc[i] = 0.f;
#pragma unroll
      for (int mm = 0; mm < 64; mm += 4) {
        const float wa = W2RR(mm), wb = W2RR(mm + 1), wc = W2RR(mm + 2), wd = W2RR(mm + 3);
        float d0 = 0.f, d1 = 0.f, d2 = 0.f, d3 = 0.f;
#pragma unroll
        for (int i = 0; i < 16; ++i) {
          const float4 g = *(const float4*)&sg2[i * 68 + mm];
          acc[i] = fmaf(g.w, wd, fmaf(g.z, wc, fmaf(g.y, wb, fmaf(g.x, wa, acc[i]))));
          d0 = fmaf(s[i], g.x, d0); d1 = fmaf(s[i], g.y, d1);
          d2 = fmaf(s[i], g.z, d2); d3 = fmaf(s[i], g.w, d3);
        }
        W2RR(mm + 0) -= d0; W2RR(mm + 1) -= d1; W2RR(mm + 2) -= d2; W2RR(mm + 3) -= d3;
      }
#pragma unroll
      for (int i = 0; i < 16; ++i) sTmp[i * 256 + n] = acc[i];
    }
    __syncthreads();

    // ---- P5: A: Z1b finalize -> sZ1b | B: stage next XB/XC tiles --------
    if (isA) {
#pragma unroll
      for (int j = 0; j < 16; ++j) G1R(j) = sTmp[j * 256 + n];
#pragma unroll
      for (int i = 0; i < 16; ++i) {
        float at = 0.f;
#pragma unroll
        for (int j = 0; j <= i; ++j) at = fmaf(sA1[i * 17 + j], G1R(j), at);
        ZBR(i) = fmaf(-sCoBuf[cur * 16 + i], at, ZBR(i));
        sZ1b[i * 260 + n] = ZBR(i);
      }
    } else {
      const int row = n >> 4, col4 = (n & 15) * 4;
      *(float4*)&sXB[nxt][row * 68 + col4] = vnb;
      *(float4*)&sXC[nxt][row * 68 + col4] = vnc;
    }
    __syncthreads();

    // ---- P6: A: Attn2 + W1 update | B: Z2b partials + W2 col update -----
    if (isA) {
      const int ia = n >> 4, ja = n & 15;
      float a0 = 0.f, a1 = 0.f, a2 = 0.f, a3 = 0.f;
      if (ja <= ia) {
#pragma unroll
        for (int kk = 0; kk < 256; kk += 16) {
          const float4 p0 = *(const float4*)&sZ1b[ia * 260 + kk];
          const float4 z0 = *(const float4*)&sZ1 [ja * 260 + kk];
          const float4 p1 = *(const float4*)&sZ1b[ia * 260 + kk + 4];
          const float4 z1 = *(const float4*)&sZ1 [ja * 260 + kk + 4];
          const float4 p2 = *(const float4*)&sZ1b[ia * 260 + kk + 8];
          const float4 z2 = *(const float4*)&sZ1 [ja * 260 + kk + 8];
          const float4 p3 = *(const float4*)&sZ1b[ia * 260 + kk + 12];
          const float4 z3 = *(const float4*)&sZ1 [ja * 260 + kk + 12];
          a0 = fmaf(p0.w, z0.w, fmaf(p0.z, z0.z, fmaf(p0.y, z0.y, fmaf(p0.x, z0.x, a0))));
          a1 = fmaf(p1.w, z1.w, fmaf(p1.z, z1.z, fmaf(p1.y, z1.y, fmaf(p1.x, z1.x, a1))));
          a2 = fmaf(p2.w, z2.w, fmaf(p2.z, z2.z, fmaf(p2.y, z2.y, fmaf(p2.x, z2.x, a2))));
          a3 = fmaf(p3.w, z3.w, fmaf(p3.z, z3.z, fmaf(p3.y, z3.y, fmaf(p3.x, z3.x, a3))));
        }
      }
      sA2[ia * 17 + ja] = (a0 + a1) + (a2 + a3);
      // W1 update: w1[k] -= cl * sum_i g1[i][n] * XB[i][k]
#pragma unroll
      for (int k = 0; k < 64; k += 4) {
        float d0 = 0.f, d1 = 0.f, d2 = 0.f, d3 = 0.f;
#pragma unroll
        for (int i = 0; i < 16; ++i) {
          const float4 x = *(const float4*)&sXBc[i * 68 + k];
          d0 = fmaf(G1R(i), x.x, d0); d1 = fmaf(G1R(i), x.y, d1);
          d2 = fmaf(G1R(i), x.z, d2); d3 = fmaf(G1R(i), x.w, d3);
        }
        W1R(k + 0) -= cl * d0; W1R(k + 1) -= cl * d1;
        W1R(k + 2) -= cl * d2; W1R(k + 3) -= cl * d3;
      }
    } else {
      const int qo = q << 6;
      // Z2b partials (pre-update w2c)
      float acc[16];
#pragma unroll
      for (int i = 0; i < 16; ++i) acc[i] = 0.f;
#pragma unroll
      for (int kk = 0; kk < 64; kk += 4) {
        const float wa = W2CR(kk), wb = W2CR(kk + 1), wc = W2CR(kk + 2), wd = W2CR(kk + 3);
#pragma unroll
        for (int i = 0; i < 16; ++i) {
          const float4 z = *(const float4*)&sZ1b[i * 260 + qo + kk];
          acc[i] = fmaf(z.w, wd, fmaf(z.z, wc, fmaf(z.y, wb, fmaf(z.x, wa, acc[i]))));
        }
      }
#pragma unroll
      for (int i = 0; i < 16; ++i) sTmp[(q << 10) + (i << 6) + m] = acc[i];
      // W2 col update: w2c[kk] -= cl * sum_i Z1[i][qo+kk] * g2[i][m]
      float s2[16];
#pragma unroll
      for (int i = 0; i < 16; ++i) s2[i] = cl * sg2[i * 68 + m];
#pragma unroll
      for (int kk = 0; kk < 64; kk += 4) {
        float d0 = 0.f, d1 = 0.f, d2 = 0.f, d3 = 0.f;
#pragma unroll
        for (int i = 0; i < 16; ++i) {
          const float4 z = *(const float4*)&sZ1[i * 260 + qo + kk];
          d0 = fmaf(s2[i], z.x, d0); d1 = fmaf(s2[i], z.y, d1);
          d2 = fmaf(s2[i], z.z, d2); d3 = fmaf(s2[i], z.w, d3);
        }
        W2CR(kk + 0) -= d0; W2CR(kk + 1) -= d1; W2CR(kk + 2) -= d2; W2CR(kk + 3) -= d3;
      }
    }
    __syncthreads();

    // ---- P7: A: Z2b combine + store (B proceeds; safe: next writes to
    //      sTmp/sA2/sg2/sCoBuf[cur] are >=2 barriers away, P1 writes only
    //      sZ1/sA1 which P7 does not read) -------------------------------
    if (isA) {
      const int q4 = n >> 6, mm = n & 63;
#pragma unroll
      for (int r = 0; r < 4; ++r) {
        const int i = q4 + 4 * r;
        float v = sTmp[i * 64 + mm] + sTmp[1024 + i * 64 + mm]
                + sTmp[2048 + i * 64 + mm] + sTmp[3072 + i * 64 + mm];
        float at = 0.f;
#pragma unroll
        for (int j = 0; j < 16; ++j) at = fmaf(sA2[i * 17 + j], sg2[j * 68 + mm], at);
        Out[cb + i * 1024 + mm] = v - sCoBuf[cur * 16 + i] * at;
      }
    }
  }
#undef W1R
#undef ZBR
#undef G1R
#undef W2RR
#undef W2CR
}

// ---------------------------------------------------------------------------
// Workspace (fp32 floats): bXC [0,16.7M) | bXB [16.7M,33.5M) | bZ2b
// [33.5M,50.3M) | bCo [50.3M,+262k).  193 MiB total.  XA (V proj) lives in
// d_out until the final GEMM overwrites it (stream-ordered, safe).
// ---------------------------------------------------------------------------
extern "C" void kernel_launch(void* const* d_in, const int* in_sizes, int n_in,
                              void* d_out, int out_size, void* d_ws, size_t ws_size,
                              hipStream_t stream)
{
  const float* H    = (const float*)d_in[0];
  const float* Wq   = (const float*)d_in[1];
  const float* Wk   = (const float*)d_in[2];
  const float* Wv   = (const float*)d_in[3];
  const float* Wo   = (const float*)d_in[4];
  const float* Wil  = (const float*)d_in[5];
  const float* bil  = (const float*)d_in[6];
  const float* W1   = (const float*)d_in[7];
  const float* W2   = (const float*)d_in[8];
  float* out        = (float*)d_out;

  float* ws    = (float*)d_ws;
  float* bXC   = ws;
  float* bXB   = ws + 16777216;
  float* bZ2b  = ws + 33554432;
  float* bCo   = ws + 50331648;
  float* bXA   = out;

  const int M = Bsz * Lsz, N = Csz, K = Csz;
  dim3 gg(N / 64, M / 64);
  dim3 bb(256);

  gemm64<<<gg, bb, 0, stream>>>(H, Wq, bXC, M, N, K);
  gemm64<<<gg, bb, 0, stream>>>(H, Wk, bXB, M, N, K);
  gemm64<<<gg, bb, 0, stream>>>(H, Wv, bXA, M, N, K);
  ilr_coeff<<<M / 4, 256, 0, stream>>>(H, Wil, bil, bCo);
  ttt_scan<<<Bsz * NHsz, 512, 0, stream>>>(bXA, bXB, bXC, bCo, W1, W2, bZ2b);
  gemm64<<<gg, bb, 0, stream>>>(bZ2b, Wo, out, M, N, K);
}

// Round 4
// 11211.749 us; speedup vs baseline: 1.3181x; 1.0324x over previous
//
#include <hip/hip_runtime.h>

#define Bsz  4
#define Lsz  4096
#define Csz  1024
#define NHsz 16
#define CSsz 16
#define HFsz 64
#define HF4sz 256
#define NCsz 256

// ---------------------------------------------------------------------------
// fp32 GEMM: C[M,N] = A[M,K] @ B[K,N].  64x64 tile, BK=16, 4x4 microtile.
// (unchanged)
// ---------------------------------------------------------------------------
__global__ __launch_bounds__(256)
void gemm64(const float* __restrict__ A, const float* __restrict__ Bm,
            float* __restrict__ Cm, int M, int N, int K)
{
  __shared__ __attribute__((aligned(16))) float As[16][68];
  __shared__ __attribute__((aligned(16))) float Bs[16][64];
  const int t  = threadIdx.x;
  const int tx = t & 15, ty = t >> 4;
  const int row0 = blockIdx.y * 64, col0 = blockIdx.x * 64;
  const int ar = t >> 2, ak = (t & 3) * 4;
  const int bk = t >> 4, bc = (t & 15) * 4;
  float acc[4][4] = {};

  for (int k0 = 0; k0 < K; k0 += 16) {
    float4 a4 = *(const float4*)&A[(size_t)(row0 + ar) * K + k0 + ak];
    float4 b4 = *(const float4*)&Bm[(size_t)(k0 + bk) * N + col0 + bc];
    As[ak + 0][ar] = a4.x; As[ak + 1][ar] = a4.y;
    As[ak + 2][ar] = a4.z; As[ak + 3][ar] = a4.w;
    *(float4*)&Bs[bk][bc] = b4;
    __syncthreads();
#pragma unroll
    for (int kk = 0; kk < 16; ++kk) {
      float4 av = *(const float4*)&As[kk][ty * 4];
      float4 bv = *(const float4*)&Bs[kk][tx * 4];
      acc[0][0] += av.x * bv.x; acc[0][1] += av.x * bv.y;
      acc[0][2] += av.x * bv.z; acc[0][3] += av.x * bv.w;
      acc[1][0] += av.y * bv.x; acc[1][1] += av.y * bv.y;
      acc[1][2] += av.y * bv.z; acc[1][3] += av.y * bv.w;
      acc[2][0] += av.z * bv.x; acc[2][1] += av.z * bv.y;
      acc[2][2] += av.z * bv.z; acc[2][3] += av.z * bv.w;
      acc[3][0] += av.w * bv.x; acc[3][1] += av.w * bv.y;
      acc[3][2] += av.w * bv.z; acc[3][3] += av.w * bv.w;
    }
    __syncthreads();
  }
#pragma unroll
  for (int r = 0; r < 4; ++r) {
    float4 v = make_float4(acc[r][0], acc[r][1], acc[r][2], acc[r][3]);
    *(float4*)&Cm[(size_t)(row0 + ty * 4 + r) * N + col0 + tx * 4] = v;
  }
}

// ---------------------------------------------------------------------------
// ilr -> coeff table (unchanged)
// ---------------------------------------------------------------------------
__global__ __launch_bounds__(256)
void ilr_coeff(const float* __restrict__ H, const float* __restrict__ Wil,
               const float* __restrict__ bil, float* __restrict__ coeff)
{
  __shared__ float sRow[4][1024];
  __shared__ float sP[4][16][17];
  const int t = threadIdx.x;
  const size_t r0 = (size_t)blockIdx.x * 4;
  for (int rr = 0; rr < 4; ++rr)
    for (int c = t; c < 1024; c += 256)
      sRow[rr][c] = H[(r0 + rr) * 1024 + c];
  __syncthreads();
  const int hh = t & 15, sl = t >> 4;
  for (int rr = 0; rr < 4; ++rr) {
    float acc = 0.f;
    for (int kk = 0; kk < 64; ++kk)
      acc += sRow[rr][sl * 64 + kk] * Wil[(sl * 64 + kk) * 16 + hh];
    sP[rr][sl][hh] = acc;
  }
  __syncthreads();
  if (t < 64) {
    const int rr = t >> 4, h2 = t & 15;
    float s = 0.f;
    for (int sl2 = 0; sl2 < 16; ++sl2) s += sP[rr][sl2][h2];
    s += bil[h2];
    const float sig = 1.f / (1.f + expf(-s));
    const int r  = (int)(r0 + rr);
    const int b  = r >> 12, l = r & 4095, nc = l >> 4, cs = l & 15;
    coeff[((b * 16 + h2) * NCsz + nc) * CSsz + cs] = sig / ((float)(cs + 1) * 64.0f);
  }
}

// ---------------------------------------------------------------------------
// TTT scan v5.
//
// Round-3 post-mortem: spills eliminated (WRITE 66MB = Out) but dur back at
// v1 level; 3 different schedules all give 36.4us/chunk -> shared fixed
// resource.  Count: ~9500 wave-level DS instructions per CU per chunk on ONE
// LDS pipe x ~9 cyc = 87k cyc = measured chunk time.  LDS pipe is saturated.
//
// v5: divert all global-backed broadcast streams off the LDS pipe:
//  * A-P1/P2/P6-W1up read XB/XC directly from global with wave-UNIFORM
//    addresses -> compiler emits s_load (SMEM pipe, SGPR operands); these
//    were 768 of A's ~900 ds_read_b128 per chunk.
//  * B-P1 Attn1 reads its per-lane XB/XC rows from global (VMEM, L1/L2-hot).
//  * sXB/sXC LDS tiles + staging writes + XB/XC prefetch machinery deleted.
//  * LDS now holds only computed intermediates; sTmp re-padded so total LDS
//    stays 82432B (preserves v4's 1-WG/CU occupancy regime).
// DS instr/CU/chunk: ~9500 -> ~6300, spread more evenly across phases.
// ---------------------------------------------------------------------------
__global__ __launch_bounds__(512) __attribute__((amdgpu_waves_per_eu(1, 2)))
void ttt_scan(const float* __restrict__ XA, const float* __restrict__ XBuf,
              const float* __restrict__ XCbuf, const float* __restrict__ coeff,
              const float* __restrict__ W1g, const float* __restrict__ W2g,
              float* __restrict__ Out)
{
  __shared__ __attribute__((aligned(16))) float sg2[16 * 68];
  __shared__ __attribute__((aligned(16))) float sZ1[16 * 260];
  __shared__ __attribute__((aligned(16))) float sZ1b[16 * 260];
  // first 4096 used ([4][16][64] partials | [16][256] g1); tail pads total
  // LDS to 82432B -> only 1 WG/CU fits -> 2-waves/EU reg budget heuristic.
  __shared__ __attribute__((aligned(16))) float sTmp[10624];
  __shared__ float sA1[16 * 17];
  __shared__ float sA2[16 * 17];
  __shared__ float sCoBuf[2 * 16];

  const int t   = threadIdx.x;
  const int bh  = blockIdx.x;             // 0..63
  const int b   = bh >> 4, h = bh & 15;
  const bool isA = (t < 256);
  const int n   = t & 255;                // A: W1 column / B: W2 row
  const int m   = t & 63, q = (t >> 6) & 3;

  // Overlaid persistent state: A: w1=[0:64], zb=[64:80], g1v=[80:96].
  // B: w2r=[0:64], w2c=[64:128].  All indices compile-time constant.
  float wreg[128];
#define W1R(k)  wreg[(k)]
#define ZBR(i)  wreg[64 + (i)]
#define G1R(i)  wreg[80 + (i)]
#define W2RR(k) wreg[(k)]
#define W2CR(k) wreg[64 + (k)]

  float xa0, xa1;  // XA prefetch (all threads)

  const float* W1h = W1g + h * HFsz * HF4sz;
  const float* W2h = W2g + h * HF4sz * HFsz;
  if (isA) {
#pragma unroll
    for (int k = 0; k < 64; ++k) W1R(k) = W1h[k * 256 + n];
  } else {
#pragma unroll
    for (int mm = 0; mm < 64; ++mm) W2RR(mm) = W2h[n * 64 + mm];
#pragma unroll
    for (int kk = 0; kk < 64; ++kk) W2CR(kk) = W2h[(q * 64 + kk) * 64 + m];
  }

  // ---- pre-loop: coeff chunk 0 + XA prefetch ----------------------------
  {
    const int cb0 = (b * Lsz) * Csz + h * HFsz;
    if (t < 16) sCoBuf[t] = coeff[(bh * NCsz + 0) * CSsz + t];
    const int ibr = t >> 6, mm = t & 63;
    xa0 = XA[cb0 + ibr * 1024 + mm];
    xa1 = XA[cb0 + (ibr + 8) * 1024 + mm];
  }
  __syncthreads();

#pragma unroll 1
  for (int nc = 0; nc < NCsz; ++nc) {
    const int cur = nc & 1, nxt = cur ^ 1;
    const int cb  = (b * Lsz + nc * CSsz) * Csz + h * HFsz;
    const int nc1 = (nc + 1) & (NCsz - 1);
    const int cb1 = (b * Lsz + nc1 * CSsz) * Csz + h * HFsz;
    const float* __restrict__ xbG = XBuf  + cb;   // 16 rows, stride 1024
    const float* __restrict__ xcG = XCbuf + cb;

    const float cl = sCoBuf[cur * 16 + 15];
    float conext = 0.f;
    if (isA && t < 16) conext = coeff[(bh * NCsz + nc1) * CSsz + t];

    // ---- P1: A: Z1 = XB@W1 -> sZ1 (XB via uniform/SMEM loads)
    //          B: Attn1 = tril(XC@XB^T) (per-lane global rows) -------------
    if (isA) {
      float acc[16];
#pragma unroll
      for (int i = 0; i < 16; ++i) {
        float a0 = 0.f, a1 = 0.f;
#pragma unroll
        for (int k = 0; k < 64; k += 8) {
          const float4 x0 = *(const float4*)&xbG[i * 1024 + k];
          const float4 x1 = *(const float4*)&xbG[i * 1024 + k + 4];
          a0 = fmaf(x0.w, W1R(k + 3), fmaf(x0.z, W1R(k + 2),
               fmaf(x0.y, W1R(k + 1), fmaf(x0.x, W1R(k), a0))));
          a1 = fmaf(x1.w, W1R(k + 7), fmaf(x1.z, W1R(k + 6),
               fmaf(x1.y, W1R(k + 5), fmaf(x1.x, W1R(k + 4), a1))));
        }
        acc[i] = a0 + a1;
      }
#pragma unroll
      for (int i = 0; i < 16; ++i) sZ1[i * 260 + n] = acc[i];
    } else {
      const int ia = n >> 4, ja = n & 15;
      float a0 = 0.f, a1 = 0.f;
      if (ja <= ia) {
#pragma unroll
        for (int k = 0; k < 64; k += 8) {
          const float4 c0 = *(const float4*)&xcG[ia * 1024 + k];
          const float4 b0 = *(const float4*)&xbG[ja * 1024 + k];
          const float4 c1 = *(const float4*)&xcG[ia * 1024 + k + 4];
          const float4 b1 = *(const float4*)&xbG[ja * 1024 + k + 4];
          a0 = fmaf(c0.w, b0.w, fmaf(c0.z, b0.z, fmaf(c0.y, b0.y, fmaf(c0.x, b0.x, a0))));
          a1 = fmaf(c1.w, b1.w, fmaf(c1.z, b1.z, fmaf(c1.y, b1.y, fmaf(c1.x, b1.x, a1))));
        }
      }
      sA1[ia * 17 + ja] = a0 + a1;
    }
    __syncthreads();

    // ---- P2: A: z1bp = XC@W1 -> zb regs (XC uniform; no LDS at all)
    //          B: Z2 partials -> sTmp ------------------------------------
    if (isA) {
#pragma unroll
      for (int i = 0; i < 16; ++i) {
        float a0 = 0.f, a1 = 0.f;
#pragma unroll
        for (int k = 0; k < 64; k += 8) {
          const float4 x0 = *(const float4*)&xcG[i * 1024 + k];
          const float4 x1 = *(const float4*)&xcG[i * 1024 + k + 4];
          a0 = fmaf(x0.w, W1R(k + 3), fmaf(x0.z, W1R(k + 2),
               fmaf(x0.y, W1R(k + 1), fmaf(x0.x, W1R(k), a0))));
          a1 = fmaf(x1.w, W1R(k + 7), fmaf(x1.z, W1R(k + 6),
               fmaf(x1.y, W1R(k + 5), fmaf(x1.x, W1R(k + 4), a1))));
        }
        ZBR(i) = a0 + a1;
      }
    } else {
      const int qo = q << 6;
      float acc[16];
#pragma unroll
      for (int i = 0; i < 16; ++i) acc[i] = 0.f;
#pragma unroll
      for (int kk = 0; kk < 64; kk += 4) {
        const float wa = W2CR(kk), wb = W2CR(kk + 1), wc = W2CR(kk + 2), wd = W2CR(kk + 3);
#pragma unroll
        for (int i = 0; i < 16; ++i) {
          const float4 z = *(const float4*)&sZ1[i * 260 + qo + kk];
          acc[i] = fmaf(z.w, wd, fmaf(z.z, wc, fmaf(z.y, wb, fmaf(z.x, wa, acc[i]))));
        }
      }
#pragma unroll
      for (int i = 0; i < 16; ++i) sTmp[(q << 10) + (i << 6) + m] = acc[i];
    }
    __syncthreads();

    // ---- P3: all: g2 = reduce(Z2 partials) - XA -> sg2 ; stage coeff ----
    {
      const int ibr = t >> 6, mm = t & 63;
      const int i1 = ibr + 8;
      float v0 = sTmp[ibr * 64 + mm] + sTmp[1024 + ibr * 64 + mm]
               + sTmp[2048 + ibr * 64 + mm] + sTmp[3072 + ibr * 64 + mm] - xa0;
      float v1 = sTmp[i1 * 64 + mm] + sTmp[1024 + i1 * 64 + mm]
               + sTmp[2048 + i1 * 64 + mm] + sTmp[3072 + i1 * 64 + mm] - xa1;
      sg2[ibr * 68 + mm] = v0;
      sg2[i1 * 68 + mm]  = v1;
      xa0 = XA[cb1 + ibr * 1024 + mm];
      xa1 = XA[cb1 + i1 * 1024 + mm];
      if (t < 16) sCoBuf[nxt * 16 + t] = conext;
    }
    __syncthreads();

    // ---- P4: B: g1 = g2@W2^T -> sTmp[16][256]  +  W2 row update ---------
    if (!isA) {
      float s[16];
#pragma unroll
      for (int i = 0; i < 16; ++i) s[i] = cl * sZ1[i * 260 + n];
      float acc[16];
#pragma unroll
      for (int i = 0; i < 16; ++i) acc[i] = 0.f;
#pragma unroll
      for (int mm = 0; mm < 64; mm += 4) {
        const float wa = W2RR(mm), wb = W2RR(mm + 1), wc = W2RR(mm + 2), wd = W2RR(mm + 3);
        float d0 = 0.f, d1 = 0.f, d2 = 0.f, d3 = 0.f;
#pragma unroll
        for (int i = 0; i < 16; ++i) {
          const float4 g = *(const float4*)&sg2[i * 68 + mm];
          acc[i] = fmaf(g.w, wd, fmaf(g.z, wc, fmaf(g.y, wb, fmaf(g.x, wa, acc[i]))));
          d0 = fmaf(s[i], g.x, d0); d1 = fmaf(s[i], g.y, d1);
          d2 = fmaf(s[i], g.z, d2); d3 = fmaf(s[i], g.w, d3);
        }
        W2RR(mm + 0) -= d0; W2RR(mm + 1) -= d1; W2RR(mm + 2) -= d2; W2RR(mm + 3) -= d3;
      }
#pragma unroll
      for (int i = 0; i < 16; ++i) sTmp[i * 256 + n] = acc[i];
    }
    __syncthreads();

    // ---- P5: A: Z1b finalize -> sZ1b (B idle) ---------------------------
    if (isA) {
#pragma unroll
      for (int j = 0; j < 16; ++j) G1R(j) = sTmp[j * 256 + n];
#pragma unroll
      for (int i = 0; i < 16; ++i) {
        float at = 0.f;
#pragma unroll
        for (int j = 0; j <= i; ++j) at = fmaf(sA1[i * 17 + j], G1R(j), at);
        ZBR(i) = fmaf(-sCoBuf[cur * 16 + i], at, ZBR(i));
        sZ1b[i * 260 + n] = ZBR(i);
      }
    }
    __syncthreads();

    // ---- P6: A: Attn2 + W1 update (XB uniform) | B: Z2b + W2 col update -
    if (isA) {
      const int ia = n >> 4, ja = n & 15;
      float a0 = 0.f, a1 = 0.f, a2 = 0.f, a3 = 0.f;
      if (ja <= ia) {
#pragma unroll
        for (int kk = 0; kk < 256; kk += 16) {
          const float4 p0 = *(const float4*)&sZ1b[ia * 260 + kk];
          const float4 z0 = *(const float4*)&sZ1 [ja * 260 + kk];
          const float4 p1 = *(const float4*)&sZ1b[ia * 260 + kk + 4];
          const float4 z1 = *(const float4*)&sZ1 [ja * 260 + kk + 4];
          const float4 p2 = *(const float4*)&sZ1b[ia * 260 + kk + 8];
          const float4 z2 = *(const float4*)&sZ1 [ja * 260 + kk + 8];
          const float4 p3 = *(const float4*)&sZ1b[ia * 260 + kk + 12];
          const float4 z3 = *(const float4*)&sZ1 [ja * 260 + kk + 12];
          a0 = fmaf(p0.w, z0.w, fmaf(p0.z, z0.z, fmaf(p0.y, z0.y, fmaf(p0.x, z0.x, a0))));
          a1 = fmaf(p1.w, z1.w, fmaf(p1.z, z1.z, fmaf(p1.y, z1.y, fmaf(p1.x, z1.x, a1))));
          a2 = fmaf(p2.w, z2.w, fmaf(p2.z, z2.z, fmaf(p2.y, z2.y, fmaf(p2.x, z2.x, a2))));
          a3 = fmaf(p3.w, z3.w, fmaf(p3.z, z3.z, fmaf(p3.y, z3.y, fmaf(p3.x, z3.x, a3))));
        }
      }
      sA2[ia * 17 + ja] = (a0 + a1) + (a2 + a3);
      // W1 update, i-outer so w1[] regs are the accumulators (64 chains):
#pragma unroll
      for (int i = 0; i < 16; ++i) {
        const float gi = cl * G1R(i);
#pragma unroll
        for (int k = 0; k < 64; k += 4) {
          const float4 x = *(const float4*)&xbG[i * 1024 + k];
          W1R(k + 0) -= gi * x.x; W1R(k + 1) -= gi * x.y;
          W1R(k + 2) -= gi * x.z; W1R(k + 3) -= gi * x.w;
        }
      }
    } else {
      const int qo = q << 6;
      // Z2b partials (pre-update w2c)
      float acc[16];
#pragma unroll
      for (int i = 0; i < 16; ++i) acc[i] = 0.f;
#pragma unroll
      for (int kk = 0; kk < 64; kk += 4) {
        const float wa = W2CR(kk), wb = W2CR(kk + 1), wc = W2CR(kk + 2), wd = W2CR(kk + 3);
#pragma unroll
        for (int i = 0; i < 16; ++i) {
          const float4 z = *(const float4*)&sZ1b[i * 260 + qo + kk];
          acc[i] = fmaf(z.w, wd, fmaf(z.z, wc, fmaf(z.y, wb, fmaf(z.x, wa, acc[i]))));
        }
      }
#pragma unroll
      for (int i = 0; i < 16; ++i) sTmp[(q << 10) + (i << 6) + m] = acc[i];
      // W2 col update: w2c[kk] -= cl * sum_i Z1[i][qo+kk] * g2[i][m]
      float s2[16];
#pragma unroll
      for (int i = 0; i < 16; ++i) s2[i] = cl * sg2[i * 68 + m];
#pragma unroll
      for (int kk = 0; kk < 64; kk += 4) {
        float d0 = 0.f, d1 = 0.f, d2 = 0.f, d3 = 0.f;
#pragma unroll
        for (int i = 0; i < 16; ++i) {
          const float4 z = *(const float4*)&sZ1[i * 260 + qo + kk];
          d0 = fmaf(s2[i], z.x, d0); d1 = fmaf(s2[i], z.y, d1);
          d2 = fmaf(s2[i], z.z, d2); d3 = fmaf(s2[i], z.w, d3);
        }
        W2CR(kk + 0) -= d0; W2CR(kk + 1) -= d1; W2CR(kk + 2) -= d2; W2CR(kk + 3) -= d3;
      }
    }
    __syncthreads();

    // ---- P7: A: Z2b combine + store (B proceeds to next P1; safe: next
    //      P1 writes only sZ1/sA1, which P7 does not read) ----------------
    if (isA) {
      const int q4 = n >> 6, mm = n & 63;
#pragma unroll
      for (int r = 0; r < 4; ++r) {
        const int i = q4 + 4 * r;
        float v = sTmp[i * 64 + mm] + sTmp[1024 + i * 64 + mm]
                + sTmp[2048 + i * 64 + mm] + sTmp[3072 + i * 64 + mm];
        float at = 0.f;
#pragma unroll
        for (int j = 0; j < 16; ++j) at = fmaf(sA2[i * 17 + j], sg2[j * 68 + mm], at);
        Out[cb + i * 1024 + mm] = v - sCoBuf[cur * 16 + i] * at;
      }
    }
  }
#undef W1R
#undef ZBR
#undef G1R
#undef W2RR
#undef W2CR
}

// ---------------------------------------------------------------------------
// Workspace (fp32 floats): bXC [0,16.7M) | bXB [16.7M,33.5M) | bZ2b
// [33.5M,50.3M) | bCo [50.3M,+262k).  193 MiB total.  XA (V proj) lives in
// d_out until the final GEMM overwrites it (stream-ordered, safe).
// ---------------------------------------------------------------------------
extern "C" void kernel_launch(void* const* d_in, const int* in_sizes, int n_in,
                              void* d_out, int out_size, void* d_ws, size_t ws_size,
                              hipStream_t stream)
{
  const float* H    = (const float*)d_in[0];
  const float* Wq   = (const float*)d_in[1];
  const float* Wk   = (const float*)d_in[2];
  const float* Wv   = (const float*)d_in[3];
  const float* Wo   = (const float*)d_in[4];
  const float* Wil  = (const float*)d_in[5];
  const float* bil  = (const float*)d_in[6];
  const float* W1   = (const float*)d_in[7];
  const float* W2   = (const float*)d_in[8];
  float* out        = (float*)d_out;

  float* ws    = (float*)d_ws;
  float* bXC   = ws;
  float* bXB   = ws + 16777216;
  float* bZ2b  = ws + 33554432;
  float* bCo   = ws + 50331648;
  float* bXA   = out;

  const int M = Bsz * Lsz, N = Csz, K = Csz;
  dim3 gg(N / 64, M / 64);
  dim3 bb(256);

  gemm64<<<gg, bb, 0, stream>>>(H, Wq, bXC, M, N, K);
  gemm64<<<gg, bb, 0, stream>>>(H, Wk, bXB, M, N, K);
  gemm64<<<gg, bb, 0, stream>>>(H, Wv, bXA, M, N, K);
  ilr_coeff<<<M / 4, 256, 0, stream>>>(H, Wil, bil, bCo);
  ttt_scan<<<Bsz * NHsz, 512, 0, stream>>>(bXA, bXB, bXC, bCo, W1, W2, bZ2b);
  gemm64<<<gg, bb, 0, stream>>>(bZ2b, Wo, out, M, N, K);
}